// Round 4
// baseline (9977.538 us; speedup 1.0000x reference)
//
#include <hip/hip_runtime.h>
#include <cstdint>
#include <cstddef>

typedef unsigned int   u32;
typedef unsigned short u16;
typedef unsigned long long u64;
typedef __attribute__((ext_vector_type(8))) short bf16x8;   // 8 bf16 = 4 VGPR
typedef __attribute__((ext_vector_type(4))) float f32x4;

#define B_  512
#define T_  168
#define H_  512

// ---------------- workspace layout (bytes). Requires ws_size >= 16MB + 8KB ----
#define OFF_U1P   (0u)                    // packed U1   bf16 [16kc][128ng][64][8]  (2MB)
#define OFF_UW2P  (2u*1024*1024)          // packed W2;U2 bf16 [32kc][128ng][64][8] (4MB)
#define OFF_H1    (6u*1024*1024)          // h1 ring, 8 slots x 1MB
#define OFF_H2    (14u*1024*1024)         // h2 ring, 2 slots x 1MB
#define OFF_FLAGS (16u*1024*1024)         // done counters (256B stride per bi)
#define H_SLOT    524288u                 // u16 elems per slot = 2planes*32bg*16kc*64*8
#define NRING     8
#define FSTRIDE   64                      // ints per flag slot (256B, no false sharing)

__device__ __forceinline__ u16 f2bf(float v){              // RNE f32->bf16
  u32 u = __float_as_uint(v);
  return (u16)((u + 0x7fffu + ((u >> 16) & 1u)) >> 16);
}
__device__ __forceinline__ float bf2f(u16 b){ return __uint_as_float(((u32)b) << 16); }
__device__ __forceinline__ float sigm(float x){ return 1.f/(1.f + __expf(-x)); }
__device__ __forceinline__ float tanh_f(float x){          // overflow-safe tanh
  float e = __expf(-2.f*fabsf(x));
  float t = (1.f - e)/(1.f + e);
  return (x < 0.f) ? -t : t;
}
// AGENT scope (sc1): bypasses non-coherent XCD L2s, write-back at LLC, relaxed
// ops emit no cache-maintenance. (Round-1: per-poll acquire buffer_inv storm.
// Round-2: SYSTEM scope wrote through to HBM.)
__device__ __forceinline__ void spin_ge(int* p, int target){
  while (__hip_atomic_load(p, __ATOMIC_RELAXED, __HIP_MEMORY_SCOPE_AGENT) < target)
    __builtin_amdgcn_s_sleep(1);
}
__device__ __forceinline__ void async_cp16(const void* g, void* l){
  __builtin_amdgcn_global_load_lds((const __attribute__((address_space(1))) u32*)g,
                                   (__attribute__((address_space(3))) u32*)l, 16, 0, 0);
}
__device__ __forceinline__ bf16x8 ring_ld16(const u16* p){
  union { u64 q[2]; bf16x8 v; } u;
  u.q[0] = __hip_atomic_load((const u64*)p,     __ATOMIC_RELAXED, __HIP_MEMORY_SCOPE_AGENT);
  u.q[1] = __hip_atomic_load(((const u64*)p)+1, __ATOMIC_RELAXED, __HIP_MEMORY_SCOPE_AGENT);
  return u.v;
}
__device__ __forceinline__ void ring_st16(u16* p, uint4 v){
  u64 lo = ((u64)v.y << 32) | v.x;
  u64 hi = ((u64)v.w << 32) | v.z;
  __hip_atomic_store((u64*)p,     lo, __ATOMIC_RELAXED, __HIP_MEMORY_SCOPE_AGENT);
  __hip_atomic_store(((u64*)p)+1, hi, __ATOMIC_RELAXED, __HIP_MEMORY_SCOPE_AGENT);
}

// ---------------- weight packing: B-operand fragment layout ------------------
// dst[((kc*128+ng)*64+ln)*8+j] = U[kc*32 + (ln>>4)*8 + j][ng*16 + (ln&15)]
__global__ void pack_w_kernel(const float* __restrict__ U1, const float* __restrict__ W2,
                              const float* __restrict__ U2, u16* __restrict__ U1p,
                              u16* __restrict__ UW2p)
{
  int idx = blockIdx.x*256 + threadIdx.x;
  int ln = idx & 63;
  int q8 = ((ln >> 4) << 3);
  int cl = ln & 15;
  if (idx < 16*128*64) {
    int kc = idx >> 13, ng = (idx >> 6) & 127;
    int row0 = kc*32 + q8, col = ng*16 + cl;
    u16* d = U1p + (size_t)idx*8;
    #pragma unroll
    for (int j=0;j<8;j++) d[j] = f2bf(U1[(size_t)(row0+j)*2048 + col]);
  } else {
    int i2 = idx - 16*128*64;
    if (i2 >= 32*128*64) return;
    int kc = i2 >> 13, ng = (i2 >> 6) & 127;
    int row0 = kc*32 + q8, col = ng*16 + cl;
    u16* d = UW2p + (size_t)i2*8;
    #pragma unroll
    for (int j=0;j<8;j++){
      int r = row0 + j;
      float v = (r < 512) ? W2[(size_t)r*2048 + col] : U2[(size_t)(r-512)*2048 + col];
      d[j] = f2bf(v);
    }
  }
}

__global__ void init_kernel(float* __restrict__ out, const float* __restrict__ fcb,
                            int* __restrict__ flags)
{
  int i = blockIdx.x*256 + threadIdx.x;
  if (i < 2048) flags[i] = 0;
  if (i < B_*T_) out[i] = fcb[0];
}

// ---------------- main persistent pipelined kernel ---------------------------
// ROUND-4 RESTRUCTURE: ring-read fabric traffic scales with #hj-blocks per bi
// (each re-reads the full K-range of h, L2-bypassed, 8-16x redundant => was
// ~40MB/step, the measured bottleneck). Halve block counts, double tiles:
// Layer1: blocks 0..31  : bi=blk>>2 (64 batch rows), hj=blk&3 (128 h cols)
// Layer2: blocks 32..95 : bi=(blk-32)>>3,            hj=(blk-32)&7 (64 h cols)
// => ring reads 20MB/step. Weight slice 512KB/block/step streamed from XCD L2
// (%8 round-robin gives each XCD 1 L1-slice + 1 L2-slice = 1MB resident).
// Wave w owns batch rows [w*16, w*16+16) (M-split) so all 4 gates of a (b,h)
// element land in the same lane -> c stays in registers.

template<int LAYER>
__device__ __forceinline__ void stage_B(u16* buf, const u16* __restrict__ Upak,
                                        int hj, int g, int w, int ln)
{
  constexpr int NGW = (LAYER==1)?32:16;  // ng tiles per block
  constexpr int GKC = (LAYER==1)?1:2;    // kc per group (group = 32KB LDS)
  constexpr int SUBW = NGW/4;            // ng tiles per gate
  #pragma unroll
  for (int p=0;p<8;p++){
    int pid = w*8 + p;                   // 32 pieces, wave-uniform piece id
    int kci = pid / NGW;
    int ngl = pid % NGW;
    int gate = ngl / SUBW;
    int sub  = ngl % SUBW;
    int ng   = gate*32 + hj*SUBW + sub;
    int kc   = g*GKC + kci;
    const u16* src = Upak + ((size_t)(kc*128 + ng)*64 + ln)*8;
    u16* dst = buf + (size_t)(kci*NGW + ngl)*512;      // wave-uniform LDS base
    async_cp16(src, dst);
  }
}

template<int LAYER>
__device__ __forceinline__ void preload_A(bf16x8* areg, const u16* __restrict__ A1,
                                          const u16* __restrict__ A2, int bg, int g, int ln)
{
  constexpr int GKC = (LAYER==1)?1:2;
  #pragma unroll
  for (int kci=0;kci<GKC;kci++){
    int kc = g*GKC + kci;
    const u16* base = A1; int kcl = kc;
    if (LAYER==2 && kc >= 16){ base = A2; kcl = kc - 16; }  // h2_{t-1} half
    #pragma unroll
    for (int pl=0; pl<2; pl++)   // pl=0: h_hi, pl=1: h_lo
      areg[kci*2+pl] = ring_ld16(base + ((size_t)(pl*32 + bg)*16 + kcl)*512 + (size_t)ln*8);
  }
}

template<int LAYER>
__device__ void run_layer(u16 (*Bbuf)[16384], int blk,
                          const float* __restrict__ inp,
                          const float* __restrict__ W1,
                          const float* __restrict__ V,
                          const float* __restrict__ bias,
                          const float* __restrict__ fcw,
                          char* __restrict__ ws,
                          float* __restrict__ out)
{
  constexpr int HT  = (LAYER==1)?128:64;  // h cols per block
  constexpr int HGN = HT/16;              // 16-col groups per gate (8 / 4)
  constexpr int NGW = 4*HGN;              // acc tiles per wave (32 / 16)
  constexpr int GKC = (LAYER==1)?1:2;     // kc per staging group
  constexpr int RS  = (LAYER==1)?136:72;  // h_lds row stride (u16), padded
  constexpr int KCP = (LAYER==1)?4:2;     // ring kc tiles this block produces
  constexpr int NPIECE = 2*4*KCP;         // pack pieces (32 / 16)

  const int tid = threadIdx.x;
  const int w    = tid >> 6;
  const int ln   = tid & 63;
  const int col  = ln & 15;
  const int quad = ln >> 4;
  const int bi = (LAYER==1) ? (blk >> 2) : ((blk-32) >> 3);
  const int hj = (LAYER==1) ? (blk & 3)  : ((blk-32) & 7);
  const int h0 = hj * HT;
  const int bg = bi*4 + w;                // this wave's global 16-row group

  const u16* Upak = (const u16*)(ws + ((LAYER==1)?OFF_U1P:OFF_UW2P));
  const u16* H1r  = (const u16*)(ws + OFF_H1);
  const u16* H2r  = (const u16*)(ws + OFF_H2);
  u16* Hw  = (u16*)(ws + ((LAYER==1)?OFF_H1:OFF_H2));
  int* done1 = (int*)(ws + OFF_FLAGS);            // L1 tiles done: 4/step/bi
  int* done2 = (int*)(ws + OFF_FLAGS) + 1024;     // L2 tiles done: 8/step/bi
  u16* hlds  = &Bbuf[0][0];   // aliases Bbuf[0..1] (dead at epilogue); L1 needs
                              // 2*64*136 = 17408 u16 < 32768 available

  float fcwr[HGN];
  if (LAYER==2){
    #pragma unroll
    for (int hg=0; hg<HGN; hg++) fcwr[hg] = fcw[h0 + hg*16 + col];
  }
  float c[HGN*4];
  #pragma unroll
  for (int i=0;i<HGN*4;i++) c[i] = 0.f;
  const f32x4 vzero = {0.f,0.f,0.f,0.f};

  // Prestage group 0 of step 0 (B is t-independent). L1 skips: its t=0 K-loop
  // is empty and its epilogue writes hlds (= Bbuf) -- would race.
  if (LAYER==2) stage_B<LAYER>(Bbuf[0], Upak, hj, 0, w, ln);

  for (int t=0; t<T_; t++){
    // ---- producer/consumer flag sync (tid0 spins, block barrier broadcasts)
    if (tid == 0){
      if (LAYER==1){
        if (t > 0)      spin_ge(&done1[bi*FSTRIDE], 4*t);           // h1[t-1] ready
        if (t >= NRING) spin_ge(&done2[bi*FSTRIDE], 8*(t-NRING+1)); // ring back-pressure
      } else {
        spin_ge(&done1[bi*FSTRIDE], 4*(t+1));                       // h1[t] ready
        if (t > 0) spin_ge(&done2[bi*FSTRIDE], 8*t);                // h2[t-1] ready
      }
      __builtin_amdgcn_fence(__ATOMIC_ACQUIRE, "workgroup");    // compiler ordering only
    }
    __syncthreads();

    f32x4 acc[NGW];
    #pragma unroll
    for (int i=0;i<NGW;i++) acc[i] = vzero;

    const int ngroups = (LAYER==1) ? (t>0 ? 16 : 0) : (t>0 ? 16 : 8);
    if (ngroups > 0){
      const u16* A1; const u16* A2 = nullptr;
      if (LAYER==1) A1 = H1r + (size_t)((t-1)%NRING)*H_SLOT;
      else { A1 = H1r + (size_t)(t%NRING)*H_SLOT;
             if (t>0) A2 = H2r + (size_t)((t-1)&1)*H_SLOT; }

      bf16x8 acur[GKC*2], anxt[GKC*2];
      // Bbuf[0] holds prestaged group 0 (issued before the spin last step).
      preload_A<LAYER>(acur, A1, A2, bg, 0, ln);
      __syncthreads();                       // drain prestage(0) + A(0)
      for (int g=0; g<ngroups; g++){
        if (g+1 < ngroups){                  // prefetch next group while computing
          stage_B<LAYER>(Bbuf[(g+1)&1], Upak, hj, g+1, w, ln);
          preload_A<LAYER>(anxt, A1, A2, bg, g+1, ln);
        }
        #pragma unroll
        for (int kci=0; kci<GKC; kci++){
          const bf16x8 ah = acur[kci*2+0];
          const bf16x8 al = acur[kci*2+1];
          #pragma unroll
          for (int ngl=0; ngl<NGW; ngl++){
            const bf16x8 bf = *(const bf16x8*)&Bbuf[g&1][(size_t)(kci*NGW+ngl)*512 + ln*8];
            acc[ngl] = __builtin_amdgcn_mfma_f32_16x16x32_bf16(ah, bf, acc[ngl], 0, 0, 0);
            acc[ngl] = __builtin_amdgcn_mfma_f32_16x16x32_bf16(al, bf, acc[ngl], 0, 0, 0);
          }
        }
        #pragma unroll
        for (int i=0;i<GKC*2;i++) acur[i] = anxt[i];
        __syncthreads();
      }
    }

    // ---- epilogue: pre-terms + gate nonlinearities + state update (fp32) ----
    float inv[4][5];
    #pragma unroll
    for (int r=0;r<4;r++){
      const float* ip = inp + ((size_t)(bi*64 + w*16 + quad*4 + r)*T_ + t)*5;
      #pragma unroll
      for (int k=0;k<5;k++) inv[r][k] = ip[k];
    }
    float fcp[4] = {0.f,0.f,0.f,0.f};
    #pragma unroll
    for (int hg=0; hg<HGN; hg++){
      float wv[4][6];
      #pragma unroll
      for (int gate=0; gate<4; gate++){
        int gcol = gate*512 + h0 + hg*16 + col;   // i,f,g,o at +0,+512,+1024,+1536
        wv[gate][0] = bias[gcol];
        wv[gate][1] = V[gcol];
        wv[gate][2] = V[2048 + gcol];
        wv[gate][3] = V[4096 + gcol];
        wv[gate][4] = V[6144 + gcol];
        wv[gate][5] = (LAYER==1) ? W1[gcol] : 0.f;
      }
      #pragma unroll
      for (int r=0;r<4;r++){
        float gv[4];
        #pragma unroll
        for (int gate=0; gate<4; gate++){
          float p = wv[gate][0]
                  + inv[r][0]*wv[gate][1] + inv[r][1]*wv[gate][2]
                  + inv[r][2]*wv[gate][3] + inv[r][3]*wv[gate][4];
          if (LAYER==1) p += inv[r][4]*wv[gate][5];   // counts * W1
          gv[gate] = acc[gate*HGN + hg][r] + p;
        }
        float ig = sigm(gv[0]);
        float fg = sigm(gv[1]);
        float gg = tanh_f(gv[2]);
        float og = sigm(gv[3]);
        float cn = fg*c[hg*4+r] + ig*gg;
        c[hg*4+r] = cn;
        float h = og*tanh_f(cn);
        if (LAYER==2) fcp[r] += h*fcwr[hg];
        u16 hi = f2bf(h);
        u16 lo = f2bf(h - bf2f(hi));      // split precision: h = hi + lo
        int bl = w*16 + quad*4 + r;
        int hc = hg*16 + col;
        hlds[bl*RS + hc] = hi;
        hlds[64*RS + bl*RS + hc] = lo;
      }
    }
    if (LAYER==2){                         // fused FC: reduce over h within block
      #pragma unroll
      for (int r=0;r<4;r++){
        #pragma unroll
        for (int m=1;m<16;m<<=1) fcp[r] += __shfl_xor(fcp[r], m, 16);
      }
      if (col == 0){
        #pragma unroll
        for (int r=0;r<4;r++)
          atomicAdd(&out[(size_t)(bi*64 + w*16 + quad*4 + r)*T_ + t], fcp[r]);
      }
    }
    __syncthreads();

    // ---- pack h tile to global ring in A-fragment layout (agent-scope) ------
    {
      u16* dst = Hw + (size_t)((LAYER==1) ? (t % NRING) : (t & 1))*H_SLOT;
      #pragma unroll
      for (int it=0; it<NPIECE*64/256; it++){
        int cidx = tid + it*256;
        int piece = cidx >> 6, lp = cidx & 63;
        int plane, bgi, kci;
        if (LAYER==1){ plane = piece >> 4; bgi = (piece >> 2) & 3; kci = piece & 3; }
        else         { plane = piece >> 3; bgi = (piece >> 1) & 3; kci = piece & 1; }
        int row = bgi*16 + (lp & 15);
        int hc  = kci*32 + ((lp >> 4) << 3);
        uint4 v = *(const uint4*)&hlds[(size_t)plane*64*RS + (size_t)row*RS + hc];
        int kcg = hj*KCP + kci;
        ring_st16(&dst[(((size_t)(plane*32 + bi*4 + bgi)*16 + kcg)*64 + lp)*8], v);
      }
    }
    __syncthreads();   // per-thread vmcnt(0) drain before s_barrier => all pack
                       // stores complete at LLC before the flag release below.
    // Release FIRST (consumers see the flag one LLC hop earlier), then prestage.
    if (tid == 0){
      __builtin_amdgcn_fence(__ATOMIC_RELEASE, "workgroup");    // compiler ordering only
      int* dp = (LAYER==1) ? &done1[bi*FSTRIDE] : &done2[bi*FSTRIDE];
      __hip_atomic_fetch_add(dp, 1, __ATOMIC_RELAXED, __HIP_MEMORY_SCOPE_AGENT);
    }
    // Prestage next step's group 0 into Bbuf[0] (free now; overlaps spin)
    if (t+1 < T_) stage_B<LAYER>(Bbuf[0], Upak, hj, 0, w, ln);
  }
}

__global__ void __launch_bounds__(256, 1)
lstm_main(const float* __restrict__ inp, const float* __restrict__ W1,
          const float* __restrict__ V1, const float* __restrict__ b1,
          const float* __restrict__ V2, const float* __restrict__ b2,
          const float* __restrict__ fcw, char* __restrict__ ws, float* __restrict__ out)
{
  __shared__ __align__(16) u16 Bbuf[2][16384];   // 64KB: double-buffered B stage
  int blk = blockIdx.x;
  if (blk < 32) run_layer<1>(Bbuf, blk, inp, W1, V1, b1, nullptr, ws, out);
  else          run_layer<2>(Bbuf, blk, inp, nullptr, V2, b2, fcw, ws, out);
}

extern "C" void kernel_launch(void* const* d_in, const int* in_sizes, int n_in,
                              void* d_out, int out_size, void* d_ws, size_t ws_size,
                              hipStream_t stream) {
  const float* inp = (const float*)d_in[0];
  const float* W1  = (const float*)d_in[1];
  const float* U1  = (const float*)d_in[2];
  const float* V1  = (const float*)d_in[3];
  const float* b1  = (const float*)d_in[4];
  const float* W2  = (const float*)d_in[5];
  const float* U2  = (const float*)d_in[6];
  const float* V2  = (const float*)d_in[7];
  const float* b2  = (const float*)d_in[8];
  const float* fcw = (const float*)d_in[9];
  const float* fcb = (const float*)d_in[10];
  char* ws = (char*)d_ws;
  float* out = (float*)d_out;

  pack_w_kernel<<<1536, 256, 0, stream>>>(U1, W2, U2,
      (u16*)(ws + OFF_U1P), (u16*)(ws + OFF_UW2P));
  init_kernel<<<(B_*T_ + 255)/256, 256, 0, stream>>>(out, fcb, (int*)(ws + OFF_FLAGS));
  // 96 blocks <= 256 CUs at 1 block/CU min occupancy -> all co-resident,
  // safe for flag-based spin sync without cooperative launch.
  lstm_main<<<96, 256, 0, stream>>>(inp, W1, V1, b1, V2, b2, fcw, ws, out);
}

// Round 5
// 2582.237 us; speedup vs baseline: 3.8639x; 3.8639x over previous
//
#include <hip/hip_runtime.h>
#include <cstdint>
#include <cstddef>

typedef unsigned int   u32;
typedef unsigned short u16;
typedef unsigned long long u64;
typedef __attribute__((ext_vector_type(8))) short bf16x8;   // 8 bf16 = 4 VGPR
typedef __attribute__((ext_vector_type(4))) float f32x4;

#define B_  512
#define T_  168
#define H_  512

// ---------------- workspace layout (bytes). Requires ws_size >= 16MB + 8KB ----
#define OFF_U1P   (0u)                    // packed U1   bf16 [16kc][128ng][64][8]  (2MB)
#define OFF_UW2P  (2u*1024*1024)          // packed W2;U2 bf16 [32kc][128ng][64][8] (4MB)
#define OFF_H1    (6u*1024*1024)          // h1 ring, 8 slots x 512KB
#define OFF_H2    (14u*1024*1024)         // h2 ring, 2 slots x 512KB
#define OFF_FLAGS (16u*1024*1024)         // done counters (256B stride per bi)
#define H_SLOT    262144u                 // u16 elems per slot = 32bg*16kc*64*8
#define NRING     8
#define FSTRIDE   64                      // ints per flag slot (256B, no false sharing)

__device__ __forceinline__ u16 f2bf(float v){              // RNE f32->bf16
  u32 u = __float_as_uint(v);
  return (u16)((u + 0x7fffu + ((u >> 16) & 1u)) >> 16);
}
__device__ __forceinline__ float bf2f(u16 b){ return __uint_as_float(((u32)b) << 16); }
__device__ __forceinline__ float sigm(float x){ return 1.f/(1.f + __expf(-x)); }
__device__ __forceinline__ float tanh_f(float x){          // overflow-safe tanh
  float e = __expf(-2.f*fabsf(x));
  float t = (1.f - e)/(1.f + e);
  return (x < 0.f) ? -t : t;
}
// AGENT scope (sc1): bypasses non-coherent XCD L2s, write-back at LLC, relaxed
// ops emit no cache-maintenance. (Round-1: per-poll acquire buffer_inv storm.
// Round-2: SYSTEM scope wrote through to HBM. Round-4: fatter tiles spilled
// VGPRs at 256 -> 3.7x regression; this is the r3 structure + lo-plane drop.)
__device__ __forceinline__ void spin_ge(int* p, int target){
  while (__hip_atomic_load(p, __ATOMIC_RELAXED, __HIP_MEMORY_SCOPE_AGENT) < target)
    __builtin_amdgcn_s_sleep(1);
}
__device__ __forceinline__ void async_cp16(const void* g, void* l){
  __builtin_amdgcn_global_load_lds((const __attribute__((address_space(1))) u32*)g,
                                   (__attribute__((address_space(3))) u32*)l, 16, 0, 0);
}
__device__ __forceinline__ bf16x8 ring_ld16(const u16* p){
  union { u64 q[2]; bf16x8 v; } u;
  u.q[0] = __hip_atomic_load((const u64*)p,     __ATOMIC_RELAXED, __HIP_MEMORY_SCOPE_AGENT);
  u.q[1] = __hip_atomic_load(((const u64*)p)+1, __ATOMIC_RELAXED, __HIP_MEMORY_SCOPE_AGENT);
  return u.v;
}
__device__ __forceinline__ void ring_st16(u16* p, uint4 v){
  u64 lo = ((u64)v.y << 32) | v.x;
  u64 hi = ((u64)v.w << 32) | v.z;
  __hip_atomic_store((u64*)p,     lo, __ATOMIC_RELAXED, __HIP_MEMORY_SCOPE_AGENT);
  __hip_atomic_store(((u64*)p)+1, hi, __ATOMIC_RELAXED, __HIP_MEMORY_SCOPE_AGENT);
}

// ---------------- weight packing: B-operand fragment layout ------------------
// dst[((kc*128+ng)*64+ln)*8+j] = U[kc*32 + (ln>>4)*8 + j][ng*16 + (ln&15)]
__global__ void pack_w_kernel(const float* __restrict__ U1, const float* __restrict__ W2,
                              const float* __restrict__ U2, u16* __restrict__ U1p,
                              u16* __restrict__ UW2p)
{
  int idx = blockIdx.x*256 + threadIdx.x;
  int ln = idx & 63;
  int q8 = ((ln >> 4) << 3);
  int cl = ln & 15;
  if (idx < 16*128*64) {
    int kc = idx >> 13, ng = (idx >> 6) & 127;
    int row0 = kc*32 + q8, col = ng*16 + cl;
    u16* d = U1p + (size_t)idx*8;
    #pragma unroll
    for (int j=0;j<8;j++) d[j] = f2bf(U1[(size_t)(row0+j)*2048 + col]);
  } else {
    int i2 = idx - 16*128*64;
    if (i2 >= 32*128*64) return;
    int kc = i2 >> 13, ng = (i2 >> 6) & 127;
    int row0 = kc*32 + q8, col = ng*16 + cl;
    u16* d = UW2p + (size_t)i2*8;
    #pragma unroll
    for (int j=0;j<8;j++){
      int r = row0 + j;
      float v = (r < 512) ? W2[(size_t)r*2048 + col] : U2[(size_t)(r-512)*2048 + col];
      d[j] = f2bf(v);
    }
  }
}

__global__ void init_kernel(float* __restrict__ out, const float* __restrict__ fcb,
                            int* __restrict__ flags)
{
  int i = blockIdx.x*256 + threadIdx.x;
  if (i < 2048) flags[i] = 0;
  if (i < B_*T_) out[i] = fcb[0];
}

// ---------------- main persistent pipelined kernel ---------------------------
// Layer1: blocks 0..63   : bi=blk>>3 (64 batch rows), hj=blk&7  (64 h cols)
//         (hj = blk%8 = XCD id -> same-hj blocks share an XCD's L2 weight slice)
// Layer2: blocks 64..191 : bi=(blk-64)>>4,            hj=(blk-64)&15 (32 h cols)
// Wave w owns batch rows [w*16, w*16+16) (M-split) so all 4 gates of a (b,h)
// element land in the same lane -> c stays in registers.
// h is stored SINGLE bf16 (lo-plane dropped in r5: halves MFMA, ring volume,
// A-latency chain; predicted absmax ~4e-4 vs 8.4e-4 threshold).

template<int LAYER>
__device__ __forceinline__ void stage_B(u16* buf, const u16* __restrict__ Upak,
                                        int hj, int g, int w, int ln)
{
  constexpr int NGW = (LAYER==1)?16:8;   // ng tiles per block
  constexpr int GKC = (LAYER==1)?2:4;    // kc per group  (group = 32KB)
  #pragma unroll
  for (int p=0;p<8;p++){
    int pid = w*8 + p;                   // 32 pieces, wave-uniform piece id
    int kci = pid / NGW;
    int ngl = pid % NGW;
    int gate = ngl / (NGW/4);
    int sub  = ngl % (NGW/4);
    int ng   = gate*32 + hj*(NGW/4) + sub;
    int kc   = g*GKC + kci;
    const u16* src = Upak + ((size_t)(kc*128 + ng)*64 + ln)*8;
    u16* dst = buf + (size_t)(kci*NGW + ngl)*512;      // wave-uniform LDS base
    async_cp16(src, dst);
  }
}

template<int LAYER>
__device__ __forceinline__ void preload_A(bf16x8* areg, const u16* __restrict__ A1,
                                          const u16* __restrict__ A2, int bg, int g, int ln)
{
  constexpr int GKC = (LAYER==1)?2:4;
  #pragma unroll
  for (int kci=0;kci<GKC;kci++){
    int kc = g*GKC + kci;
    const u16* base = A1; int kcl = kc;
    if (LAYER==2 && kc >= 16){ base = A2; kcl = kc - 16; }  // h2_{t-1} half
    areg[kci] = ring_ld16(base + ((size_t)bg*16 + kcl)*512 + (size_t)ln*8);
  }
}

template<int LAYER>
__device__ void run_layer(u16 (*Bbuf)[16384], int blk,
                          const float* __restrict__ inp,
                          const float* __restrict__ W1,
                          const float* __restrict__ V,
                          const float* __restrict__ bias,
                          const float* __restrict__ fcw,
                          char* __restrict__ ws,
                          float* __restrict__ out)
{
  constexpr int HT  = (LAYER==1)?64:32;   // h cols per block
  constexpr int HGN = (LAYER==1)?4:2;     // 16-col groups per gate
  constexpr int NGW = (LAYER==1)?16:8;    // acc tiles per wave
  constexpr int GKC = (LAYER==1)?2:4;     // kc per staging group
  constexpr int RS  = (LAYER==1)?72:40;   // h_lds row stride (u16), padded
  constexpr int KCP = (LAYER==1)?2:1;     // ring kc tiles this block produces
  constexpr int NPIECE = 4*KCP;           // pack pieces (8 / 4)

  const int tid = threadIdx.x;
  const int w    = tid >> 6;
  const int ln   = tid & 63;
  const int col  = ln & 15;
  const int quad = ln >> 4;
  const int bi = (LAYER==1) ? (blk >> 3) : ((blk-64) >> 4);
  const int hj = (LAYER==1) ? (blk & 7)  : ((blk-64) & 15);
  const int h0 = hj * HT;
  const int bg = bi*4 + w;                // this wave's global 16-row group

  const u16* Upak = (const u16*)(ws + ((LAYER==1)?OFF_U1P:OFF_UW2P));
  const u16* H1r  = (const u16*)(ws + OFF_H1);
  const u16* H2r  = (const u16*)(ws + OFF_H2);
  u16* Hw  = (u16*)(ws + ((LAYER==1)?OFF_H1:OFF_H2));
  int* done1 = (int*)(ws + OFF_FLAGS);            // L1 tiles done: 8/step/bi
  int* done2 = (int*)(ws + OFF_FLAGS) + 1024;     // L2 tiles done: 16/step/bi
  u16* hlds  = &Bbuf[0][0];               // aliased into Bbuf[0] (dead at epilogue)

  float fcwr[HGN];
  if (LAYER==2){
    #pragma unroll
    for (int hg=0; hg<HGN; hg++) fcwr[hg] = fcw[h0 + hg*16 + col];
  }
  float c[HGN*4];
  #pragma unroll
  for (int i=0;i<HGN*4;i++) c[i] = 0.f;
  const f32x4 vzero = {0.f,0.f,0.f,0.f};

  // Prestage group 0 of step 0 (B is t-independent). L1 skips: its t=0 K-loop
  // is empty and its epilogue writes hlds (= Bbuf[0]) -- a prestage in flight
  // there would race.
  if (LAYER==2) stage_B<LAYER>(Bbuf[0], Upak, hj, 0, w, ln);

  for (int t=0; t<T_; t++){
    // ---- producer/consumer flag sync (tid0 spins, block barrier broadcasts)
    if (tid == 0){
      if (LAYER==1){
        if (t > 0)      spin_ge(&done1[bi*FSTRIDE], 8*t);            // h1[t-1] ready
        if (t >= NRING) spin_ge(&done2[bi*FSTRIDE], 16*(t-NRING+1)); // ring back-pressure
      } else {
        spin_ge(&done1[bi*FSTRIDE], 8*(t+1));                        // h1[t] ready
        if (t > 0) spin_ge(&done2[bi*FSTRIDE], 16*t);                // h2[t-1] ready
      }
      __builtin_amdgcn_fence(__ATOMIC_ACQUIRE, "workgroup");    // compiler ordering only
    }
    __syncthreads();

    f32x4 acc[NGW];
    #pragma unroll
    for (int i=0;i<NGW;i++) acc[i] = vzero;

    const int ngroups = (LAYER==1) ? (t>0 ? 8 : 0) : (t>0 ? 8 : 4);
    if (ngroups > 0){
      const u16* A1; const u16* A2 = nullptr;
      if (LAYER==1) A1 = H1r + (size_t)((t-1)%NRING)*H_SLOT;
      else { A1 = H1r + (size_t)(t%NRING)*H_SLOT;
             if (t>0) A2 = H2r + (size_t)((t-1)&1)*H_SLOT; }

      bf16x8 acur[GKC], anxt[GKC];
      // Bbuf[0] holds prestaged group 0 (issued before the spin last step).
      preload_A<LAYER>(acur, A1, A2, bg, 0, ln);
      __syncthreads();                       // drain prestage(0) + A(0)
      for (int g=0; g<ngroups; g++){
        if (g+1 < ngroups){                  // prefetch next group while computing
          stage_B<LAYER>(Bbuf[(g+1)&1], Upak, hj, g+1, w, ln);
          preload_A<LAYER>(anxt, A1, A2, bg, g+1, ln);
        }
        #pragma unroll
        for (int kci=0; kci<GKC; kci++){
          const bf16x8 ah = acur[kci];
          #pragma unroll
          for (int ngl=0; ngl<NGW; ngl++){
            const bf16x8 bf = *(const bf16x8*)&Bbuf[g&1][(size_t)(kci*NGW+ngl)*512 + ln*8];
            acc[ngl] = __builtin_amdgcn_mfma_f32_16x16x32_bf16(ah, bf, acc[ngl], 0, 0, 0);
          }
        }
        #pragma unroll
        for (int i=0;i<GKC;i++) acur[i] = anxt[i];
        __syncthreads();
      }
    }

    // ---- epilogue: pre-terms + gate nonlinearities + state update (fp32) ----
    float inv[4][5];
    #pragma unroll
    for (int r=0;r<4;r++){
      const float* ip = inp + ((size_t)(bi*64 + w*16 + quad*4 + r)*T_ + t)*5;
      #pragma unroll
      for (int k=0;k<5;k++) inv[r][k] = ip[k];
    }
    float fcp[4] = {0.f,0.f,0.f,0.f};
    #pragma unroll
    for (int hg=0; hg<HGN; hg++){
      float wv[4][6];
      #pragma unroll
      for (int gate=0; gate<4; gate++){
        int gcol = gate*512 + h0 + hg*16 + col;   // i,f,g,o at +0,+512,+1024,+1536
        wv[gate][0] = bias[gcol];
        wv[gate][1] = V[gcol];
        wv[gate][2] = V[2048 + gcol];
        wv[gate][3] = V[4096 + gcol];
        wv[gate][4] = V[6144 + gcol];
        wv[gate][5] = (LAYER==1) ? W1[gcol] : 0.f;
      }
      #pragma unroll
      for (int r=0;r<4;r++){
        float gv[4];
        #pragma unroll
        for (int gate=0; gate<4; gate++){
          float p = wv[gate][0]
                  + inv[r][0]*wv[gate][1] + inv[r][1]*wv[gate][2]
                  + inv[r][2]*wv[gate][3] + inv[r][3]*wv[gate][4];
          if (LAYER==1) p += inv[r][4]*wv[gate][5];   // counts * W1
          gv[gate] = acc[gate*HGN + hg][r] + p;
        }
        float ig = sigm(gv[0]);
        float fg = sigm(gv[1]);
        float gg = tanh_f(gv[2]);
        float og = sigm(gv[3]);
        float cn = fg*c[hg*4+r] + ig*gg;
        c[hg*4+r] = cn;
        float h = og*tanh_f(cn);
        if (LAYER==2) fcp[r] += h*fcwr[hg];
        int bl = w*16 + quad*4 + r;
        int hc = hg*16 + col;
        hlds[bl*RS + hc] = f2bf(h);       // single-plane bf16 h
      }
    }
    if (LAYER==2){                         // fused FC: reduce over h within block
      #pragma unroll
      for (int r=0;r<4;r++){
        #pragma unroll
        for (int m=1;m<16;m<<=1) fcp[r] += __shfl_xor(fcp[r], m, 16);
      }
      if (col == 0){
        #pragma unroll
        for (int r=0;r<4;r++)
          atomicAdd(&out[(size_t)(bi*64 + w*16 + quad*4 + r)*T_ + t], fcp[r]);
      }
    }
    __syncthreads();

    // ---- pack h tile to global ring in A-fragment layout (agent-scope) ------
    {
      u16* dst = Hw + (size_t)((LAYER==1) ? (t % NRING) : (t & 1))*H_SLOT;
      // NPIECE*64 lanes of work; 256 threads -> L1: 2 iters, L2: 1 iter
      #pragma unroll
      for (int it=0; it<(NPIECE*64+255)/256; it++){
        int cidx = tid + it*256;
        if (cidx < NPIECE*64){
          int piece = cidx >> 6, lp = cidx & 63;
          int bgi, kci;
          if (LAYER==1){ bgi = (piece >> 1) & 3; kci = piece & 1; }
          else         { bgi = piece & 3;        kci = 0; }
          int row = bgi*16 + (lp & 15);
          int hc  = kci*32 + ((lp >> 4) << 3);
          uint4 v = *(const uint4*)&hlds[(size_t)row*RS + hc];
          int kcg = (LAYER==1) ? (hj*2 + kci) : hj;
          ring_st16(&dst[(((size_t)(bi*4 + bgi)*16 + kcg)*64 + lp)*8], v);
        }
      }
    }
    __syncthreads();   // per-thread vmcnt(0) drain before s_barrier => all pack
                       // stores complete at LLC before the flag release below.
    // Release FIRST (consumers see the flag one LLC hop earlier), then prestage.
    if (tid == 0){
      __builtin_amdgcn_fence(__ATOMIC_RELEASE, "workgroup");    // compiler ordering only
      int* dp = (LAYER==1) ? &done1[bi*FSTRIDE] : &done2[bi*FSTRIDE];
      __hip_atomic_fetch_add(dp, 1, __ATOMIC_RELAXED, __HIP_MEMORY_SCOPE_AGENT);
    }
    // Prestage next step's group 0 into Bbuf[0] (free now; overlaps spin)
    if (t+1 < T_) stage_B<LAYER>(Bbuf[0], Upak, hj, 0, w, ln);
  }
}

__global__ void __launch_bounds__(256, 1)
lstm_main(const float* __restrict__ inp, const float* __restrict__ W1,
          const float* __restrict__ V1, const float* __restrict__ b1,
          const float* __restrict__ V2, const float* __restrict__ b2,
          const float* __restrict__ fcw, char* __restrict__ ws, float* __restrict__ out)
{
  __shared__ __align__(16) u16 Bbuf[2][16384];   // 64KB: double-buffered B stage
  int blk = blockIdx.x;
  if (blk < 64) run_layer<1>(Bbuf, blk, inp, W1, V1, b1, nullptr, ws, out);
  else          run_layer<2>(Bbuf, blk, inp, nullptr, V2, b2, fcw, ws, out);
}

extern "C" void kernel_launch(void* const* d_in, const int* in_sizes, int n_in,
                              void* d_out, int out_size, void* d_ws, size_t ws_size,
                              hipStream_t stream) {
  const float* inp = (const float*)d_in[0];
  const float* W1  = (const float*)d_in[1];
  const float* U1  = (const float*)d_in[2];
  const float* V1  = (const float*)d_in[3];
  const float* b1  = (const float*)d_in[4];
  const float* W2  = (const float*)d_in[5];
  const float* U2  = (const float*)d_in[6];
  const float* V2  = (const float*)d_in[7];
  const float* b2  = (const float*)d_in[8];
  const float* fcw = (const float*)d_in[9];
  const float* fcb = (const float*)d_in[10];
  char* ws = (char*)d_ws;
  float* out = (float*)d_out;

  pack_w_kernel<<<1536, 256, 0, stream>>>(U1, W2, U2,
      (u16*)(ws + OFF_U1P), (u16*)(ws + OFF_UW2P));
  init_kernel<<<(B_*T_ + 255)/256, 256, 0, stream>>>(out, fcb, (int*)(ws + OFF_FLAGS));
  // 192 blocks <= 256 CUs at 1 block/CU min occupancy -> all co-resident,
  // safe for flag-based spin sync without cooperative launch.
  lstm_main<<<192, 256, 0, stream>>>(inp, W1, V1, b1, V2, b2, fcw, ws, out);
}